// Round 4
// baseline (353.004 us; speedup 1.0000x reference)
//
#include <hip/hip_runtime.h>
#include <hip/hip_bf16.h>

// Performer (FAVOR+) attention. B=4 H=8 N=4096 D=64 M=256.
// Round-10:
//  - Round-9 post-mortem: global-direct Af/Bc reads made out_kernel WORSE
//    (148us steady vs ~95 LDS-staged). VGPR_Count=44 showed the compiler
//    issued every fragment load just-in-time -> ~200cy L2 latency exposed
//    per tt/ks step, zero MLP. Occupancy 44% couldn't cover it.
//  - Fix: EXPLICIT depth-1 register prefetch pipelines. Af frags for tt+1
//    load before tt's MFMA+exp block (phi phase ~230cy covers L2 latency);
//    Bc frags for next ks-half load before current ks's 12 MFMAs. mc loop
//    fully unrolled -> all frag indices compile-time (no scratch). No
//    launch_bounds cap (round-7 lesson): VGPR lands where it lands.
//  - kside/fixup/prep unchanged (round-8 validated) for attribution.

typedef __attribute__((ext_vector_type(8))) short short8;
typedef __attribute__((ext_vector_type(4))) float floatx4;

constexpr int BB = 4, HH = 8, NN = 4096, DD = 64, MM = 256, BH = 32;
constexpr int NCH = 16;  // n-chunks per head (ctx partial slices)
constexpr float SCALE = 0.3535533905932738f;  // 64^-0.25
constexpr float RATIO = 0.0625f;              // 256^-0.5
constexpr float EPSI  = 1e-4f;
constexpr float NEGINF = -3.4e38f;

__device__ inline unsigned pk2(float a, float b) {
  unsigned ua = __float_as_uint(a) + 0x8000u;
  unsigned ub = __float_as_uint(b) + 0x8000u;
  return (ua >> 16) | (ub & 0xffff0000u);
}
__device__ inline float hif(float x) {
  return __uint_as_float((__float_as_uint(x) + 0x8000u) & 0xffff0000u);
}
__device__ inline unsigned short bhi(float x) {
  return (unsigned short)((__float_as_uint(x) + 0x8000u) >> 16);
}
__device__ inline int ph16(int i) { return (i & 56) | ((i + (i >> 3)) & 7); }

union Frag { short8 s8; unsigned u[4]; };

__device__ inline void atomicMaxF(float* a, float v) {
  unsigned* ai = (unsigned*)a;
  unsigned old = __atomic_load_n(ai, __ATOMIC_RELAXED);
  while (__uint_as_float(old) < v) {
    unsigned assumed = old;
    old = atomicCAS(ai, assumed, __float_as_uint(v));
    if (old == assumed) break;
  }
}

// ---------------- prep: split proj; init stabk; zero small accumulators ----
__global__ __launch_bounds__(256) void prep_kernel(
    const float* __restrict__ proj, unsigned short* __restrict__ projH,
    unsigned short* __restrict__ projL, float* __restrict__ stabk,
    float* __restrict__ Vs, float* __restrict__ ctxsum,
    float* __restrict__ ksE) {
  const int i = blockIdx.x * 256 + threadIdx.x;  // 16384 elems
  float v = proj[i];
  projH[i] = bhi(v);
  projL[i] = bhi(v - hif(v));
  if (i < BH) stabk[i] = NEGINF;
  if (i < 2048) { Vs[i] = 0.f; ctxsum[i] = 0.f; }
  if (i < 8192) ksE[i] = 0.f;
}

// ---------------- kside: MFMA phi_k pass (round-8 verbatim) ----------------
// grid (NCH*2, 32), 256 thr. Block: 256 K-rows x 128 features (m-slice).
template <bool PARTIAL>
__global__ __launch_bounds__(256) void kside_kernel(
    const float* __restrict__ K, const float* __restrict__ V,
    const float* __restrict__ mask,
    const unsigned short* __restrict__ projH, const unsigned short* __restrict__ projL,
    float* __restrict__ stabk, float* __restrict__ ksE,
    float* __restrict__ ctxOut, float* __restrict__ Vs) {
  const int bh = blockIdx.y, b = bh >> 3;
  const int nch = blockIdx.x & (NCH - 1);
  const int ms  = blockIdx.x >> 4;  // m-slice 0/1
  const int t = threadIdx.x;
  const int w = t >> 6, l = t & 63, c = l & 15, sq = l >> 4;
  const int m0 = ms * 128 + w * 32;

  __shared__ __align__(16) unsigned short sK[2][32 * 72];   // [plane][n][d] pad 72
  __shared__ __align__(16) unsigned short sVt[2][64 * 40];  // [plane][e][n] pad 40
  __shared__ float sDiag[32];
  __shared__ float sRed[4];
  __shared__ float sVsum[4][64];
  __shared__ __align__(16) unsigned short sPhi[4][2][512];  // [w][plane][swizzled]

  // persistent B-frags of P^T from pre-split planes (2 m-tiles of 16)
  Frag Bp[2][2][2];
#pragma unroll
  for (int tt = 0; tt < 2; ++tt)
#pragma unroll
    for (int s = 0; s < 2; ++s) {
      const size_t o = (size_t)(m0 + tt * 16 + c) * DD + s * 32 + sq * 8;
      Bp[tt][s][0].s8 = *(const short8*)&projH[o];
      Bp[tt][s][1].s8 = *(const short8*)&projL[o];
    }

  floatx4 ctxacc[2][4];
#pragma unroll
  for (int i = 0; i < 2; ++i)
#pragma unroll
    for (int j = 0; j < 4; ++j) ctxacc[i][j] = (floatx4){0.f, 0.f, 0.f, 0.f};
  float ksac[2] = {0.f, 0.f};
  float mxloc = NEGINF;
  float vsacc = 0.f;  // masked V column-sum partial (column estar = c*4+sq)

  const int r0 = nch * 256;

  for (int ch = 0; ch < 8; ++ch) {
    const int rb = r0 + ch * 32;
    __syncthreads();

    // ---- stage K (scaled+masked, split) + diag ----
#pragma unroll
    for (int rep = 0; rep < 2; ++rep) {
      const int f = t + rep * 256;
      const int n = f >> 4, dg = f & 15;
      const float mk = mask[b * NN + rb + n];
      const float msc = mk * SCALE;
      float4 kv = *(const float4*)(K + ((size_t)bh * NN + rb + n) * DD + dg * 4);
      float k0 = kv.x * msc, k1 = kv.y * msc, k2 = kv.z * msc, k3 = kv.w * msc;
      float ss = fmaf(k0, k0, fmaf(k1, k1, fmaf(k2, k2, k3 * k3)));
      ss += __shfl_xor(ss, 1); ss += __shfl_xor(ss, 2);
      ss += __shfl_xor(ss, 4); ss += __shfl_xor(ss, 8);
      if (dg == 0) sDiag[n] = 0.5f * ss;
      unsigned h0 = pk2(k0, k1), h1 = pk2(k2, k3);
      float q0 = k0 - hif(k0), q1 = k1 - hif(k1);
      float q2 = k2 - hif(k2), q3 = k3 - hif(k3);
      *(uint2*)(&sK[0][n * 72 + dg * 4]) = make_uint2(h0, h1);
      *(uint2*)(&sK[1][n * 72 + dg * 4]) = make_uint2(pk2(q0, q1), pk2(q2, q3));
    }

    // ---- stage V^T via wave shfl-transpose; accumulate Vs partial ----
#pragma unroll
    for (int rep = 0; rep < 2; ++rep) {
      const int nb = w * 4 + rep * 16;
      const int n_loc = nb + sq;
      const float mk = mask[b * NN + rb + n_loc];
      float4 vv = *(const float4*)(V + ((size_t)bh * NN + rb + n_loc) * DD + c * 4);
      float va[4] = {vv.x * mk, vv.y * mk, vv.z * mk, vv.w * mk};
      float g[4];
#pragma unroll
      for (int k = 0; k < 4; ++k) {
        const int gi = (sq + k) & 3;
        float sel = va[(sq - k) & 3];
        g[gi] = __shfl(sel, gi * 16 + c);
      }
      const int estar = c * 4 + sq;  // lane's column, rows nb..nb+3
      vsacc += ((g[0] + g[1]) + (g[2] + g[3]));
      unsigned h0 = pk2(g[0], g[1]), h1 = pk2(g[2], g[3]);
      float q0 = g[0] - hif(g[0]), q1 = g[1] - hif(g[1]);
      float q2 = g[2] - hif(g[2]), q3 = g[3] - hif(g[3]);
      *(uint2*)(&sVt[0][estar * 40 + nb]) = make_uint2(h0, h1);
      *(uint2*)(&sVt[1][estar * 40 + nb]) = make_uint2(pk2(q0, q1), pk2(q2, q3));
    }
    __syncthreads();

    // ---- frags ----
    Frag Ak[2][2][2];
#pragma unroll
    for (int i = 0; i < 2; ++i)
#pragma unroll
      for (int s = 0; s < 2; ++s) {
        Ak[i][s][0].s8 = *(const short8*)&sK[0][(i * 16 + c) * 72 + s * 32 + sq * 8];
        Ak[i][s][1].s8 = *(const short8*)&sK[1][(i * 16 + c) * 72 + s * 32 + sq * 8];
      }
    Frag Bv[4][2];
#pragma unroll
    for (int E = 0; E < 4; ++E) {
      Bv[E][0].s8 = *(const short8*)&sVt[0][(E * 16 + c) * 40 + sq * 8];
      Bv[E][1].s8 = *(const short8*)&sVt[1][(E * 16 + c) * 40 + sq * 8];
    }

#pragma unroll
    for (int tt = 0; tt < 2; ++tt) {
      // S1: xp for both n-tiles
      floatx4 xacc[2];
#pragma unroll
      for (int i = 0; i < 2; ++i) {
        floatx4 a = (floatx4){0.f, 0.f, 0.f, 0.f};
#pragma unroll
        for (int s = 0; s < 2; ++s) {
          a = __builtin_amdgcn_mfma_f32_16x16x32_bf16(Ak[i][s][0].s8, Bp[tt][s][0].s8, a, 0, 0, 0);
          a = __builtin_amdgcn_mfma_f32_16x16x32_bf16(Ak[i][s][0].s8, Bp[tt][s][1].s8, a, 0, 0, 0);
          a = __builtin_amdgcn_mfma_f32_16x16x32_bf16(Ak[i][s][1].s8, Bp[tt][s][0].s8, a, 0, 0, 0);
        }
        xacc[i] = a;
      }
      // S2: exp frame-0, max, ksum, phi scatter (wave-local, swizzled)
      const int qp_c = sq >> 1, half = (sq & 1) * 4;
#pragma unroll
      for (int i = 0; i < 2; ++i) {
        float p[4];
#pragma unroll
        for (int jj = 0; jj < 4; ++jj) {
          float xp = xacc[i][jj];
          mxloc = fmaxf(mxloc, xp);
          p[jj] = __expf(xp - sDiag[i * 16 + sq * 4 + jj]);
          ksac[tt] += p[jj];
        }
        unsigned h0 = pk2(p[0], p[1]), h1 = pk2(p[2], p[3]);
        float q0 = p[0] - hif(p[0]), q1 = p[1] - hif(p[1]);
        float q2 = p[2] - hif(p[2]), q3 = p[3] - hif(p[3]);
        const int tl = (i * 2 + qp_c) * 16 + c;
        const int idx = ph16(tl) * 8 + half;
        *(uint2*)&sPhi[w][0][idx] = make_uint2(h0, h1);
        *(uint2*)&sPhi[w][1][idx] = make_uint2(pk2(q0, q1), pk2(q2, q3));
      }
      // S3: ctx += phi^T @ Vm (wave-local DS ordering: no barrier needed)
      Frag Ap[2];
      Ap[0].s8 = *(const short8*)&sPhi[w][0][ph16(l) * 8];
      Ap[1].s8 = *(const short8*)&sPhi[w][1][ph16(l) * 8];
#pragma unroll
      for (int E = 0; E < 4; ++E) {
        ctxacc[tt][E] = __builtin_amdgcn_mfma_f32_16x16x32_bf16(Ap[0].s8, Bv[E][0].s8, ctxacc[tt][E], 0, 0, 0);
        ctxacc[tt][E] = __builtin_amdgcn_mfma_f32_16x16x32_bf16(Ap[0].s8, Bv[E][1].s8, ctxacc[tt][E], 0, 0, 0);
        ctxacc[tt][E] = __builtin_amdgcn_mfma_f32_16x16x32_bf16(Ap[1].s8, Bv[E][0].s8, ctxacc[tt][E], 0, 0, 0);
      }
    }
  }

  // ---- epilogue: ksum partials, block max, Vs partial, ctx out ----
#pragma unroll
  for (int tt = 0; tt < 2; ++tt) {
    float v = ksac[tt];
    v += __shfl_xor(v, 16);
    v += __shfl_xor(v, 32);
    if (sq == 0) atomicAdd(&ksE[bh * MM + m0 + tt * 16 + c], v);
  }
#pragma unroll
  for (int off = 1; off <= 32; off <<= 1) mxloc = fmaxf(mxloc, __shfl_xor(mxloc, off));
  if (l == 0) sRed[w] = mxloc;
  sVsum[w][c * 4 + sq] = vsacc;
  __syncthreads();
  if (t == 0)
    atomicMaxF(&stabk[bh], fmaxf(fmaxf(sRed[0], sRed[1]), fmaxf(sRed[2], sRed[3])));
  if (ms == 0 && t < 64)
    atomicAdd(&Vs[bh * DD + t],
              (sVsum[0][t] + sVsum[1][t]) + (sVsum[2][t] + sVsum[3][t]));

  if (PARTIAL) {
    float* cg = ctxOut + ((size_t)(bh * NCH + nch) * MM) * DD;
#pragma unroll
    for (int tt = 0; tt < 2; ++tt)
#pragma unroll
      for (int E = 0; E < 4; ++E)
#pragma unroll
        for (int r = 0; r < 4; ++r)
          cg[(m0 + tt * 16 + sq * 4 + r) * DD + E * 16 + c] = ctxacc[tt][E][r];
  } else {
    float* cg = ctxOut + (size_t)bh * MM * DD;
#pragma unroll
    for (int tt = 0; tt < 2; ++tt)
#pragma unroll
      for (int E = 0; E < 4; ++E)
#pragma unroll
        for (int r = 0; r < 4; ++r)
          atomicAdd(&cg[(m0 + tt * 16 + sq * 4 + r) * DD + E * 16 + c],
                    ctxacc[tt][E][r]);
  }
}

// ---------------- fixup: reduce partials, scale+eps, emit ctxT; ksfin ------
// grid (8 mchunks of 32, 32 bh), 256 thr.
template <int NPARTS>
__global__ __launch_bounds__(256) void fixup_kernel(
    const float* __restrict__ stabk, const float* __restrict__ Vs,
    const float* __restrict__ ksE, const float* __restrict__ ctxParts,
    float* __restrict__ ksum, float* __restrict__ kssum,
    float* __restrict__ ctxsum, unsigned short* __restrict__ ctxTH,
    unsigned short* __restrict__ ctxTL) {
  const int bh = blockIdx.y, mc = blockIdx.x, t = threadIdx.x;
  const float es = __expf(-stabk[bh]);
  const int e = t & 63, g = t >> 6;
  const float vse = EPSI * Vs[bh * DD + e];

  __shared__ float tile[64 * 33];  // [e][ml] ml<32
  __shared__ float cred[256];

  float csum = 0.f;
#pragma unroll
  for (int r = 0; r < 8; ++r) {
    const int ml = r * 4 + g;        // m-local in 32-chunk
    const int m = mc * 32 + ml;
    float x = 0.f;
#pragma unroll
    for (int p = 0; p < NPARTS; ++p)
      x += ctxParts[(((size_t)bh * NPARTS + p) * MM + m) * DD + e];
    float v = RATIO * (es * x + vse);
    csum += v;
    tile[e * 33 + ml] = v;
  }
  cred[t] = csum;
  __syncthreads();
  if (t < 64)
    atomicAdd(&ctxsum[bh * DD + t],
              (cred[t] + cred[t + 64]) + (cred[t + 128] + cred[t + 192]));

  // coalesced transposed write-out
  {
    const int ml5 = t & 31, elg = t >> 5;
#pragma unroll
    for (int r = 0; r < 8; ++r) {
      const int el = r * 8 + elg;
      float v = tile[el * 33 + ml5];
      const size_t o = ((size_t)(bh * DD + el)) * MM + mc * 32 + ml5;
      ctxTH[o] = bhi(v);
      ctxTL[o] = bhi(v - hif(v));
    }
  }

  // ksfin fold (one block column per head)
  if (mc == 0) {
    __syncthreads();
    const float kv = RATIO * (es * ksE[bh * MM + t] + (float)NN * EPSI);
    ksum[bh * MM + t] = kv;
    cred[t] = kv;
    __syncthreads();
    for (int off = 128; off >= 1; off >>= 1) {
      if (t < off) cred[t] += cred[t + off];
      __syncthreads();
    }
    if (t == 0) kssum[bh] = cred[0];
  }
}

// ---------------- out: MFMA Q side, global-direct + explicit prefetch ------
__global__ __launch_bounds__(256) void out_kernel(
    const float* __restrict__ Q,
    const unsigned short* __restrict__ projH, const unsigned short* __restrict__ projL,
    const float* __restrict__ ksum,
    const unsigned short* __restrict__ ctxTH, const unsigned short* __restrict__ ctxTL,
    const float* __restrict__ kssum, const float* __restrict__ ctxsum,
    float* __restrict__ out) {
  const int bh = blockIdx.y;
  const int r0 = blockIdx.x * 64;
  const int t = threadIdx.x, w = t >> 6, l = t & 63, c = l & 15, sq = l >> 4;

  // sQ staging is dead after Bq extraction; sPhi overlaid behind a barrier.
  __shared__ __align__(16) unsigned short sMem[2 * 64 * 80];  // 20.5 KB
  __shared__ float sKs[256];
  __shared__ float sDiag[64];
#define SQ_(p, idx) sMem[(p) * 5120 + (idx)]
#define SPHI_(wv, p, ks, idx) sMem[((((wv) * 2 + (p)) * 2 + (ks)) * 512) + (idx)]

  {
    const int row = t >> 2, q4 = t & 3;
    const float* qp = Q + ((size_t)bh * NN + r0 + row) * DD + q4 * 16;
    float4 t0 = *(const float4*)(qp + 0), t1 = *(const float4*)(qp + 4),
           t2 = *(const float4*)(qp + 8), t3 = *(const float4*)(qp + 12);
    float v[16] = {t0.x, t0.y, t0.z, t0.w, t1.x, t1.y, t1.z, t1.w,
                   t2.x, t2.y, t2.z, t2.w, t3.x, t3.y, t3.z, t3.w};
    float ss = 0.f;
#pragma unroll
    for (int j = 0; j < 16; ++j) { v[j] *= SCALE; ss = fmaf(v[j], v[j], ss); }
    ss += __shfl_xor(ss, 1);
    ss += __shfl_xor(ss, 2);
    if (q4 == 0) sDiag[row] = 0.5f * ss;
    unsigned short* dh = &SQ_(0, row * 80 + q4 * 16);
    unsigned short* dl = &SQ_(1, row * 80 + q4 * 16);
#pragma unroll
    for (int j = 0; j < 8; ++j) {
      *(unsigned*)&dh[2 * j] = pk2(v[2 * j], v[2 * j + 1]);
      float l0 = v[2 * j] - hif(v[2 * j]), l1 = v[2 * j + 1] - hif(v[2 * j + 1]);
      *(unsigned*)&dl[2 * j] = pk2(l0, l1);
    }
  }
  sKs[t] = ksum[bh * MM + t];
  __syncthreads();

  Frag Bq[2][2];
#pragma unroll
  for (int s = 0; s < 2; ++s)
#pragma unroll
    for (int p = 0; p < 2; ++p)
      Bq[s][p].s8 = *(const short8*)&SQ_(p, (w * 16 + c) * 80 + s * 32 + sq * 8);

  const float diagc = sDiag[w * 16 + c];
  __syncthreads();  // protect sQ reads before sPhi overlay writes

  floatx4 oacc[4];
#pragma unroll
  for (int E = 0; E < 4; ++E) oacc[E] = (floatx4){0.f, 0.f, 0.f, 0.f};
  float mxacc = NEGINF, dsacc = 0.f;

  const unsigned short* ctxH_b = ctxTH + (size_t)bh * DD * MM;
  const unsigned short* ctxL_b = ctxTL + (size_t)bh * DD * MM;

  // ---- prefetch pipelines: Af for (mc=0,tt=0); Bc for (mc=0,ks=0) ----
  Frag AfN[2][2];
#pragma unroll
  for (int s = 0; s < 2; ++s) {
    const size_t af = (size_t)(c)*DD + s * 32 + sq * 8;
    AfN[s][0].s8 = *(const short8*)&projH[af];
    AfN[s][1].s8 = *(const short8*)&projL[af];
  }
  Frag BcN[4][2];
#pragma unroll
  for (int E = 0; E < 4; ++E) {
    const size_t bc = (size_t)(E * 16 + c) * MM + sq * 8;
    BcN[E][0].s8 = *(const short8*)&ctxH_b[bc];
    BcN[E][1].s8 = *(const short8*)&ctxL_b[bc];
  }

#pragma unroll
  for (int mc = 0; mc < 4; ++mc) {
    // ---- phi_q phase: consume AfN, prefetch next tt's Af ----
#pragma unroll
    for (int tt = 0; tt < 4; ++tt) {
      Frag Af[2][2];
#pragma unroll
      for (int s = 0; s < 2; ++s) {
        Af[s][0] = AfN[s][0];
        Af[s][1] = AfN[s][1];
      }
      if (!(mc == 3 && tt == 3)) {
        const int nmc = (tt == 3) ? mc + 1 : mc;
        const int ntt = (tt + 1) & 3;
        const size_t af = (size_t)(nmc * 64 + ntt * 16 + c) * DD + sq * 8;
#pragma unroll
        for (int s = 0; s < 2; ++s) {
          AfN[s][0].s8 = *(const short8*)&projH[af + s * 32];
          AfN[s][1].s8 = *(const short8*)&projL[af + s * 32];
        }
      }
      floatx4 x = (floatx4){0.f, 0.f, 0.f, 0.f};
#pragma unroll
      for (int s = 0; s < 2; ++s) {
        x = __builtin_amdgcn_mfma_f32_16x16x32_bf16(Af[s][0].s8, Bq[s][0].s8, x, 0, 0, 0);
        x = __builtin_amdgcn_mfma_f32_16x16x32_bf16(Af[s][0].s8, Bq[s][1].s8, x, 0, 0, 0);
        x = __builtin_amdgcn_mfma_f32_16x16x32_bf16(Af[s][1].s8, Bq[s][0].s8, x, 0, 0, 0);
      }
      float p4[4];
#pragma unroll
      for (int jj = 0; jj < 4; ++jj) {
        const float xp = x[jj];
        mxacc = fmaxf(mxacc, xp);
        p4[jj] = __expf(xp - diagc);
        dsacc = fmaf(p4[jj], sKs[mc * 64 + tt * 16 + sq * 4 + jj], dsacc);
      }
      const int kstep = tt >> 1;
      const int tl = ((tt & 1) * 2 + (sq >> 1)) * 16 + c;
      const int off = (sq & 1) * 4;
      float l0 = p4[0] - hif(p4[0]), l1 = p4[1] - hif(p4[1]);
      float l2 = p4[2] - hif(p4[2]), l3 = p4[3] - hif(p4[3]);
      *(uint2*)&SPHI_(w, 0, kstep, tl * 8 + off) = make_uint2(pk2(p4[0], p4[1]), pk2(p4[2], p4[3]));
      *(uint2*)&SPHI_(w, 1, kstep, tl * 8 + off) = make_uint2(pk2(l0, l1), pk2(l2, l3));
    }

    // ---- PV phase: consume BcN, prefetch next ks-half's Bc ----
#pragma unroll
    for (int ks = 0; ks < 2; ++ks) {
      Frag Bc[4][2];
#pragma unroll
      for (int E = 0; E < 4; ++E) {
        Bc[E][0] = BcN[E][0];
        Bc[E][1] = BcN[E][1];
      }
      if (!(mc == 3 && ks == 1)) {
        const int nmc = ks ? mc + 1 : mc;
        const int nks = ks ^ 1;
#pragma unroll
        for (int E = 0; E < 4; ++E) {
          const size_t bc = (size_t)(E * 16 + c) * MM + nmc * 64 + nks * 32 + sq * 8;
          BcN[E][0].s8 = *(const short8*)&ctxH_b[bc];
          BcN[E][1].s8 = *(const short8*)&ctxL_b[bc];
        }
      }
      Frag Aph[2];
      Aph[0].s8 = *(const short8*)&SPHI_(w, 0, ks, l * 8);
      Aph[1].s8 = *(const short8*)&SPHI_(w, 1, ks, l * 8);
#pragma unroll
      for (int E = 0; E < 4; ++E) {
        oacc[E] = __builtin_amdgcn_mfma_f32_16x16x32_bf16(Aph[0].s8, Bc[E][0].s8, oacc[E], 0, 0, 0);
        oacc[E] = __builtin_amdgcn_mfma_f32_16x16x32_bf16(Aph[0].s8, Bc[E][1].s8, oacc[E], 0, 0, 0);
        oacc[E] = __builtin_amdgcn_mfma_f32_16x16x32_bf16(Aph[1].s8, Bc[E][0].s8, oacc[E], 0, 0, 0);
      }
    }
  }
#undef SQ_
#undef SPHI_

  mxacc = fmaxf(mxacc, __shfl_xor(mxacc, 16));
  mxacc = fmaxf(mxacc, __shfl_xor(mxacc, 32));
  dsacc += __shfl_xor(dsacc, 16);
  dsacc += __shfl_xor(dsacc, 32);

  const float kss = kssum[bh];
  float fac[4], oinv[4];
#pragma unroll
  for (int jj = 0; jj < 4; ++jj) {
    const int src = sq * 4 + jj;
    const float s_row = __shfl(mxacc, src);
    const float d_row = __shfl(dsacc, src);
    const float f = __expf(s_row) * EPSI;
    fac[jj] = f;
    oinv[jj] = 1.f / (d_row + f * kss);
  }

  const float* csb = ctxsum + bh * DD;
#pragma unroll
  for (int E = 0; E < 4; ++E) {
    const float cse = csb[E * 16 + c];
#pragma unroll
    for (int jj = 0; jj < 4; ++jj) {
      const int row = r0 + w * 16 + sq * 4 + jj;
      out[((size_t)bh * NN + row) * DD + E * 16 + c] =
          (oacc[E][jj] + fac[jj] * cse) * oinv[jj];
    }
  }
}

extern "C" void kernel_launch(void* const* d_in, const int* in_sizes, int n_in,
                              void* d_out, int out_size, void* d_ws, size_t ws_size,
                              hipStream_t stream) {
  const float* Q    = (const float*)d_in[0];
  const float* K    = (const float*)d_in[1];
  const float* V    = (const float*)d_in[2];
  const float* mask = (const float*)d_in[3];
  const float* proj = (const float*)d_in[4];
  float* out = (float*)d_out;

  float* wsf = (float*)d_ws;
  float* stabk  = wsf;                          // 32
  float* ksum   = wsf + 32;                     // 8192
  float* kssum  = wsf + 8224;                   // 32
  float* Vs     = wsf + 8256;                   // 2048
  float* ctxsum = wsf + 10304;                  // 2048
  float* ksE    = wsf + 12352;                  // 8192
  unsigned short* projH = (unsigned short*)(wsf + 20544);   // 16384 shorts
  unsigned short* projL = (unsigned short*)(wsf + 28736);   // 16384 shorts
  unsigned short* ctxTH = (unsigned short*)(wsf + 36928);   // 524288 shorts
  unsigned short* ctxTL = (unsigned short*)(wsf + 299072);  // 524288 shorts
  float* ctxBig = wsf + 561216;  // PARTIAL: NCH*32*16384 = 8388608 fl (33.5MB)
                                 // fallback: 524288 fl (ctxE)

  const size_t need_partial = (size_t)(561216 + NCH * BH * MM * DD) * 4;
  const bool partial = ws_size >= need_partial;

  prep_kernel<<<64, 256, 0, stream>>>(proj, projH, projL, stabk, Vs, ctxsum, ksE);

  if (partial) {
    kside_kernel<true><<<dim3(NCH * 2, BH), 256, 0, stream>>>(
        K, V, mask, projH, projL, stabk, ksE, ctxBig, Vs);
    fixup_kernel<NCH><<<dim3(8, BH), 256, 0, stream>>>(
        stabk, Vs, ksE, ctxBig, ksum, kssum, ctxsum, ctxTH, ctxTL);
  } else {
    hipMemsetAsync(ctxBig, 0, (size_t)MM * DD * BH * 4, stream);
    kside_kernel<false><<<dim3(NCH * 2, BH), 256, 0, stream>>>(
        K, V, mask, projH, projL, stabk, ksE, ctxBig, Vs);
    fixup_kernel<1><<<dim3(8, BH), 256, 0, stream>>>(
        stabk, Vs, ksE, ctxBig, ksum, kssum, ctxsum, ctxTH, ctxTL);
  }

  out_kernel<<<dim3(64, BH), 256, 0, stream>>>(
      Q, projH, projL, ksum, ctxTH, ctxTL, kssum, ctxsum, out);
}

// Round 5
// 228.097 us; speedup vs baseline: 1.5476x; 1.5476x over previous
//
#include <hip/hip_runtime.h>
#include <hip/hip_bf16.h>

// Performer (FAVOR+) attention. B=4 H=8 N=4096 D=64 M=256.
// Round-11:
//  - out_kernel: REVERTED to the validated LDS-staged round-4 version
//    (95us steady). Global-direct variants (r9 JIT, r10 prefetch) both
//    ~150us: fragment feeding must be bulk LDS staging, not per-frag L2.
//  - kside: round-6 structure (NCH=16, no M-split, 2 blocks/CU grid-limited)
//    + T14 async-stage prefetch: issue chunk ch+1's K/V float4 loads right
//    after the staging barrier (whole MFMA phase ~1200cy hides HBM latency),
//    consume after next top barrier. NO launch_bounds cap (round-7's spill
//    lesson): +20 VGPR lands ~176 -> 8 waves/CU, same residency as round-6
//    (grid-limited at 2 blocks/CU). No occupancy loss, no spills expected.

typedef __attribute__((ext_vector_type(8))) short short8;
typedef __attribute__((ext_vector_type(4))) float floatx4;

constexpr int BB = 4, HH = 8, NN = 4096, DD = 64, MM = 256, BH = 32;
constexpr int NCH = 16;  // n-chunks per head (kside grid.x)
constexpr float SCALE = 0.3535533905932738f;  // 64^-0.25
constexpr float RATIO = 0.0625f;              // 256^-0.5
constexpr float EPSI  = 1e-4f;
constexpr float NEGINF = -3.4e38f;

__device__ inline unsigned pk2(float a, float b) {
  unsigned ua = __float_as_uint(a) + 0x8000u;
  unsigned ub = __float_as_uint(b) + 0x8000u;
  return (ua >> 16) | (ub & 0xffff0000u);
}
__device__ inline float hif(float x) {
  return __uint_as_float((__float_as_uint(x) + 0x8000u) & 0xffff0000u);
}
__device__ inline unsigned short bhi(float x) {
  return (unsigned short)((__float_as_uint(x) + 0x8000u) >> 16);
}
__device__ inline int ph16(int i) { return (i & 56) | ((i + (i >> 3)) & 7); }

union Frag { short8 s8; unsigned u[4]; };

__device__ inline void atomicMaxF(float* a, float v) {
  unsigned* ai = (unsigned*)a;
  unsigned old = __atomic_load_n(ai, __ATOMIC_RELAXED);
  while (__uint_as_float(old) < v) {
    unsigned assumed = old;
    old = atomicCAS(ai, assumed, __float_as_uint(v));
    if (old == assumed) break;
  }
}

// ---------------- prep: split proj; init stabk; zero small accumulators ----
__global__ __launch_bounds__(256) void prep_kernel(
    const float* __restrict__ proj, unsigned short* __restrict__ projH,
    unsigned short* __restrict__ projL, float* __restrict__ stabk,
    float* __restrict__ Vs, float* __restrict__ ctxsum,
    float* __restrict__ ksE) {
  const int i = blockIdx.x * 256 + threadIdx.x;  // 16384 elems
  float v = proj[i];
  projH[i] = bhi(v);
  projL[i] = bhi(v - hif(v));
  if (i < BH) stabk[i] = NEGINF;
  if (i < 2048) { Vs[i] = 0.f; ctxsum[i] = 0.f; }
  if (i < 8192) ksE[i] = 0.f;
}

// ---------------- kside: MFMA phi_k pass -----------------------------------
// grid (NCH, 32), 256 thr. Block: 256 K-rows, 8 chunks of 32, all 256 feats.
// T14 prefetch: chunk ch+1's K/V loads issued post-staging-barrier.
template <bool PARTIAL>
__global__ __launch_bounds__(256) void kside_kernel(
    const float* __restrict__ K, const float* __restrict__ V,
    const float* __restrict__ mask,
    const unsigned short* __restrict__ projH, const unsigned short* __restrict__ projL,
    float* __restrict__ stabk, float* __restrict__ ksE,
    float* __restrict__ ctxOut, float* __restrict__ Vs) {
  const int bh = blockIdx.y, b = bh >> 3;
  const int t = threadIdx.x;
  const int w = t >> 6, l = t & 63, c = l & 15, sq = l >> 4;
  const int m0 = w * 64;

  __shared__ __align__(16) unsigned short sK[2][32 * 72];   // [plane][n][d] pad 72
  __shared__ __align__(16) unsigned short sVt[2][64 * 40];  // [plane][e][n] pad 40
  __shared__ float sDiag[32];
  __shared__ float sRed[4];
  __shared__ float sVsum[4][64];
  __shared__ __align__(16) unsigned short sPhi[4][2][512];  // [w][plane][swizzled]

  // persistent B-frags of P^T from pre-split planes
  Frag Bp[4][2][2];
#pragma unroll
  for (int tt = 0; tt < 4; ++tt)
#pragma unroll
    for (int s = 0; s < 2; ++s) {
      const size_t o = (size_t)(m0 + tt * 16 + c) * DD + s * 32 + sq * 8;
      Bp[tt][s][0].s8 = *(const short8*)&projH[o];
      Bp[tt][s][1].s8 = *(const short8*)&projL[o];
    }

  floatx4 ctxacc[4][4];
#pragma unroll
  for (int i = 0; i < 4; ++i)
#pragma unroll
    for (int j = 0; j < 4; ++j) ctxacc[i][j] = (floatx4){0.f, 0.f, 0.f, 0.f};
  float ksac[4] = {0.f, 0.f, 0.f, 0.f};
  float mxloc = NEGINF;
  float vsacc = 0.f;  // masked V column-sum partial (column estar = c*4+sq)

  const int r0 = blockIdx.x * 256;

  // ---- prime prefetch for ch=0 ----
  float4 pk4[2], pv4[2];
  float pmk[2], pmv[2];
  {
    const int rb = r0;
#pragma unroll
    for (int rep = 0; rep < 2; ++rep) {
      const int f = t + rep * 256;
      const int n = f >> 4;
      pmk[rep] = mask[b * NN + rb + n];
      pk4[rep] = *(const float4*)(K + ((size_t)bh * NN + rb + n) * DD + (f & 15) * 4);
      const int n_loc = w * 4 + rep * 16 + sq;
      pmv[rep] = mask[b * NN + rb + n_loc];
      pv4[rep] = *(const float4*)(V + ((size_t)bh * NN + rb + n_loc) * DD + c * 4);
    }
  }

  for (int ch = 0; ch < 8; ++ch) {
    __syncthreads();

    // ---- stage K (scaled+masked, split) + diag, from prefetched regs ----
#pragma unroll
    for (int rep = 0; rep < 2; ++rep) {
      const int f = t + rep * 256;
      const int n = f >> 4, dg = f & 15;
      const float msc = pmk[rep] * SCALE;
      float k0 = pk4[rep].x * msc, k1 = pk4[rep].y * msc,
            k2 = pk4[rep].z * msc, k3 = pk4[rep].w * msc;
      float ss = fmaf(k0, k0, fmaf(k1, k1, fmaf(k2, k2, k3 * k3)));
      ss += __shfl_xor(ss, 1); ss += __shfl_xor(ss, 2);
      ss += __shfl_xor(ss, 4); ss += __shfl_xor(ss, 8);
      if (dg == 0) sDiag[n] = 0.5f * ss;
      unsigned h0 = pk2(k0, k1), h1 = pk2(k2, k3);
      float q0 = k0 - hif(k0), q1 = k1 - hif(k1);
      float q2 = k2 - hif(k2), q3 = k3 - hif(k3);
      *(uint2*)(&sK[0][n * 72 + dg * 4]) = make_uint2(h0, h1);
      *(uint2*)(&sK[1][n * 72 + dg * 4]) = make_uint2(pk2(q0, q1), pk2(q2, q3));
    }

    // ---- stage V^T via wave shfl-transpose; accumulate Vs partial ----
#pragma unroll
    for (int rep = 0; rep < 2; ++rep) {
      const int nb = w * 4 + rep * 16;
      const float mk = pmv[rep];
      float4 vv = pv4[rep];
      float va[4] = {vv.x * mk, vv.y * mk, vv.z * mk, vv.w * mk};
      float g[4];
#pragma unroll
      for (int k = 0; k < 4; ++k) {
        const int gi = (sq + k) & 3;
        float sel = va[(sq - k) & 3];
        g[gi] = __shfl(sel, gi * 16 + c);
      }
      const int estar = c * 4 + sq;  // lane's column, rows nb..nb+3
      vsacc += ((g[0] + g[1]) + (g[2] + g[3]));
      unsigned h0 = pk2(g[0], g[1]), h1 = pk2(g[2], g[3]);
      float q0 = g[0] - hif(g[0]), q1 = g[1] - hif(g[1]);
      float q2 = g[2] - hif(g[2]), q3 = g[3] - hif(g[3]);
      *(uint2*)(&sVt[0][estar * 40 + nb]) = make_uint2(h0, h1);
      *(uint2*)(&sVt[1][estar * 40 + nb]) = make_uint2(pk2(q0, q1), pk2(q2, q3));
    }
    __syncthreads();

    // ---- issue next chunk's loads: whole MFMA phase hides the latency ----
    if (ch < 7) {
      const int rb = r0 + (ch + 1) * 32;
#pragma unroll
      for (int rep = 0; rep < 2; ++rep) {
        const int f = t + rep * 256;
        const int n = f >> 4;
        pmk[rep] = mask[b * NN + rb + n];
        pk4[rep] = *(const float4*)(K + ((size_t)bh * NN + rb + n) * DD + (f & 15) * 4);
        const int n_loc = w * 4 + rep * 16 + sq;
        pmv[rep] = mask[b * NN + rb + n_loc];
        pv4[rep] = *(const float4*)(V + ((size_t)bh * NN + rb + n_loc) * DD + c * 4);
      }
    }

    // ---- frags ----
    Frag Ak[2][2][2];
#pragma unroll
    for (int i = 0; i < 2; ++i)
#pragma unroll
      for (int s = 0; s < 2; ++s) {
        Ak[i][s][0].s8 = *(const short8*)&sK[0][(i * 16 + c) * 72 + s * 32 + sq * 8];
        Ak[i][s][1].s8 = *(const short8*)&sK[1][(i * 16 + c) * 72 + s * 32 + sq * 8];
      }
    Frag Bv[4][2];
#pragma unroll
    for (int E = 0; E < 4; ++E) {
      Bv[E][0].s8 = *(const short8*)&sVt[0][(E * 16 + c) * 40 + sq * 8];
      Bv[E][1].s8 = *(const short8*)&sVt[1][(E * 16 + c) * 40 + sq * 8];
    }

#pragma unroll
    for (int tt = 0; tt < 4; ++tt) {
      // S1: xp for both n-tiles
      floatx4 xacc[2];
#pragma unroll
      for (int i = 0; i < 2; ++i) {
        floatx4 a = (floatx4){0.f, 0.f, 0.f, 0.f};
#pragma unroll
        for (int s = 0; s < 2; ++s) {
          a = __builtin_amdgcn_mfma_f32_16x16x32_bf16(Ak[i][s][0].s8, Bp[tt][s][0].s8, a, 0, 0, 0);
          a = __builtin_amdgcn_mfma_f32_16x16x32_bf16(Ak[i][s][0].s8, Bp[tt][s][1].s8, a, 0, 0, 0);
          a = __builtin_amdgcn_mfma_f32_16x16x32_bf16(Ak[i][s][1].s8, Bp[tt][s][0].s8, a, 0, 0, 0);
        }
        xacc[i] = a;
      }
      // S2: exp frame-0, max, ksum, phi scatter (wave-local, swizzled)
      const int qp_c = sq >> 1, half = (sq & 1) * 4;
#pragma unroll
      for (int i = 0; i < 2; ++i) {
        float p[4];
#pragma unroll
        for (int jj = 0; jj < 4; ++jj) {
          float xp = xacc[i][jj];
          mxloc = fmaxf(mxloc, xp);
          p[jj] = __expf(xp - sDiag[i * 16 + sq * 4 + jj]);
          ksac[tt] += p[jj];
        }
        unsigned h0 = pk2(p[0], p[1]), h1 = pk2(p[2], p[3]);
        float q0 = p[0] - hif(p[0]), q1 = p[1] - hif(p[1]);
        float q2 = p[2] - hif(p[2]), q3 = p[3] - hif(p[3]);
        const int tl = (i * 2 + qp_c) * 16 + c;
        const int idx = ph16(tl) * 8 + half;
        *(uint2*)&sPhi[w][0][idx] = make_uint2(h0, h1);
        *(uint2*)&sPhi[w][1][idx] = make_uint2(pk2(q0, q1), pk2(q2, q3));
      }
      // S3: ctx += phi^T @ Vm (wave-local DS ordering: no barrier needed)
      Frag Ap[2];
      Ap[0].s8 = *(const short8*)&sPhi[w][0][ph16(l) * 8];
      Ap[1].s8 = *(const short8*)&sPhi[w][1][ph16(l) * 8];
#pragma unroll
      for (int E = 0; E < 4; ++E) {
        ctxacc[tt][E] = __builtin_amdgcn_mfma_f32_16x16x32_bf16(Ap[0].s8, Bv[E][0].s8, ctxacc[tt][E], 0, 0, 0);
        ctxacc[tt][E] = __builtin_amdgcn_mfma_f32_16x16x32_bf16(Ap[0].s8, Bv[E][1].s8, ctxacc[tt][E], 0, 0, 0);
        ctxacc[tt][E] = __builtin_amdgcn_mfma_f32_16x16x32_bf16(Ap[1].s8, Bv[E][0].s8, ctxacc[tt][E], 0, 0, 0);
      }
    }
  }

  // ---- epilogue: ksum partials, block max, Vs partial, ctx out ----
#pragma unroll
  for (int tt = 0; tt < 4; ++tt) {
    float v = ksac[tt];
    v += __shfl_xor(v, 16);
    v += __shfl_xor(v, 32);
    if (sq == 0) atomicAdd(&ksE[bh * MM + m0 + tt * 16 + c], v);
  }
#pragma unroll
  for (int off = 1; off <= 32; off <<= 1) mxloc = fmaxf(mxloc, __shfl_xor(mxloc, off));
  if (l == 0) sRed[w] = mxloc;
  sVsum[w][c * 4 + sq] = vsacc;
  __syncthreads();
  if (t == 0)
    atomicMaxF(&stabk[bh], fmaxf(fmaxf(sRed[0], sRed[1]), fmaxf(sRed[2], sRed[3])));
  if (t < 64)
    atomicAdd(&Vs[bh * DD + t],
              (sVsum[0][t] + sVsum[1][t]) + (sVsum[2][t] + sVsum[3][t]));

  if (PARTIAL) {
    float* cg = ctxOut + ((size_t)(bh * NCH + blockIdx.x) * MM) * DD;
#pragma unroll
    for (int tt = 0; tt < 4; ++tt)
#pragma unroll
      for (int E = 0; E < 4; ++E)
#pragma unroll
        for (int r = 0; r < 4; ++r)
          cg[(m0 + tt * 16 + sq * 4 + r) * DD + E * 16 + c] = ctxacc[tt][E][r];
  } else {
    float* cg = ctxOut + (size_t)bh * MM * DD;
#pragma unroll
    for (int tt = 0; tt < 4; ++tt)
#pragma unroll
      for (int E = 0; E < 4; ++E)
#pragma unroll
        for (int r = 0; r < 4; ++r)
          atomicAdd(&cg[(m0 + tt * 16 + sq * 4 + r) * DD + E * 16 + c],
                    ctxacc[tt][E][r]);
  }
}

// ---------------- fixup: reduce partials, scale+eps, emit ctxT; ksfin ------
// grid (8 mchunks of 32, 32 bh), 256 thr.
template <int NPARTS>
__global__ __launch_bounds__(256) void fixup_kernel(
    const float* __restrict__ stabk, const float* __restrict__ Vs,
    const float* __restrict__ ksE, const float* __restrict__ ctxParts,
    float* __restrict__ ksum, float* __restrict__ kssum,
    float* __restrict__ ctxsum, unsigned short* __restrict__ ctxTH,
    unsigned short* __restrict__ ctxTL) {
  const int bh = blockIdx.y, mc = blockIdx.x, t = threadIdx.x;
  const float es = __expf(-stabk[bh]);
  const int e = t & 63, g = t >> 6;
  const float vse = EPSI * Vs[bh * DD + e];

  __shared__ float tile[64 * 33];  // [e][ml] ml<32
  __shared__ float cred[256];

  float csum = 0.f;
#pragma unroll
  for (int r = 0; r < 8; ++r) {
    const int ml = r * 4 + g;        // m-local in 32-chunk
    const int m = mc * 32 + ml;
    float x = 0.f;
#pragma unroll
    for (int p = 0; p < NPARTS; ++p)
      x += ctxParts[(((size_t)bh * NPARTS + p) * MM + m) * DD + e];
    float v = RATIO * (es * x + vse);
    csum += v;
    tile[e * 33 + ml] = v;
  }
  cred[t] = csum;
  __syncthreads();
  if (t < 64)
    atomicAdd(&ctxsum[bh * DD + t],
              (cred[t] + cred[t + 64]) + (cred[t + 128] + cred[t + 192]));

  // coalesced transposed write-out
  {
    const int ml5 = t & 31, elg = t >> 5;
#pragma unroll
    for (int r = 0; r < 8; ++r) {
      const int el = r * 8 + elg;
      float v = tile[el * 33 + ml5];
      const size_t o = ((size_t)(bh * DD + el)) * MM + mc * 32 + ml5;
      ctxTH[o] = bhi(v);
      ctxTL[o] = bhi(v - hif(v));
    }
  }

  // ksfin fold (one block column per head)
  if (mc == 0) {
    __syncthreads();
    const float kv = RATIO * (es * ksE[bh * MM + t] + (float)NN * EPSI);
    ksum[bh * MM + t] = kv;
    cred[t] = kv;
    __syncthreads();
    for (int off = 128; off >= 1; off >>= 1) {
      if (t < off) cred[t] += cred[t + off];
      __syncthreads();
    }
    if (t == 0) kssum[bh] = cred[0];
  }
}

// ---------------- out: MFMA Q side (round-4 verbatim, validated) -----------
__global__ __launch_bounds__(256, 2) void out_kernel(
    const float* __restrict__ Q,
    const unsigned short* __restrict__ projH, const unsigned short* __restrict__ projL,
    const float* __restrict__ ksum,
    const unsigned short* __restrict__ ctxTH, const unsigned short* __restrict__ ctxTL,
    const float* __restrict__ kssum, const float* __restrict__ ctxsum,
    float* __restrict__ out) {
  const int bh = blockIdx.y;
  const int r0 = blockIdx.x * 64;
  const int t = threadIdx.x, w = t >> 6, l = t & 63, c = l & 15, sq = l >> 4;

  __shared__ __align__(16) unsigned short sQ[2][64 * 80];
  __shared__ __align__(16) unsigned short sP[2][64 * 80];
  __shared__ __align__(16) unsigned short sC[2][64 * 80];
  __shared__ float sKs[256];
  __shared__ float sDiag[64];
  __shared__ __align__(16) unsigned short sPhi[4][2][2][512];

  {
    const int row = t >> 2, q4 = t & 3;
    const float* qp = Q + ((size_t)bh * NN + r0 + row) * DD + q4 * 16;
    float4 t0 = *(const float4*)(qp + 0), t1 = *(const float4*)(qp + 4),
           t2 = *(const float4*)(qp + 8), t3 = *(const float4*)(qp + 12);
    float v[16] = {t0.x, t0.y, t0.z, t0.w, t1.x, t1.y, t1.z, t1.w,
                   t2.x, t2.y, t2.z, t2.w, t3.x, t3.y, t3.z, t3.w};
    float ss = 0.f;
#pragma unroll
    for (int j = 0; j < 16; ++j) { v[j] *= SCALE; ss = fmaf(v[j], v[j], ss); }
    ss += __shfl_xor(ss, 1);
    ss += __shfl_xor(ss, 2);
    if (q4 == 0) sDiag[row] = 0.5f * ss;
    unsigned short* dh = &sQ[0][row * 80 + q4 * 16];
    unsigned short* dl = &sQ[1][row * 80 + q4 * 16];
#pragma unroll
    for (int j = 0; j < 8; ++j) {
      *(unsigned*)&dh[2 * j] = pk2(v[2 * j], v[2 * j + 1]);
      float l0 = v[2 * j] - hif(v[2 * j]), l1 = v[2 * j + 1] - hif(v[2 * j + 1]);
      *(unsigned*)&dl[2 * j] = pk2(l0, l1);
    }
  }
  sKs[t] = ksum[bh * MM + t];
  __syncthreads();

  Frag Bq[2][2];
#pragma unroll
  for (int s = 0; s < 2; ++s)
#pragma unroll
    for (int p = 0; p < 2; ++p)
      Bq[s][p].s8 = *(const short8*)&sQ[p][(w * 16 + c) * 80 + s * 32 + sq * 8];

  const float diagc = sDiag[w * 16 + c];
  floatx4 oacc[4];
#pragma unroll
  for (int E = 0; E < 4; ++E) oacc[E] = (floatx4){0.f, 0.f, 0.f, 0.f};
  float mxacc = NEGINF, dsacc = 0.f;

  for (int mc = 0; mc < 4; ++mc) {
    __syncthreads();
    {
      const int row = t >> 2, q4 = t & 3;
      const size_t gp = (size_t)(mc * 64 + row) * DD + q4 * 16;
      const uint4* ph = (const uint4*)&projH[gp];
      const uint4* pl = (const uint4*)&projL[gp];
      *(uint4*)&sP[0][row * 80 + q4 * 16] = ph[0];
      *(uint4*)&sP[0][row * 80 + q4 * 16 + 8] = ph[1];
      *(uint4*)&sP[1][row * 80 + q4 * 16] = pl[0];
      *(uint4*)&sP[1][row * 80 + q4 * 16 + 8] = pl[1];
      const size_t gc = ((size_t)bh * DD + row) * MM + mc * 64 + q4 * 16;
      const uint4* chh = (const uint4*)&ctxTH[gc];
      const uint4* cll = (const uint4*)&ctxTL[gc];
      *(uint4*)&sC[0][row * 80 + q4 * 16] = chh[0];
      *(uint4*)&sC[0][row * 80 + q4 * 16 + 8] = chh[1];
      *(uint4*)&sC[1][row * 80 + q4 * 16] = cll[0];
      *(uint4*)&sC[1][row * 80 + q4 * 16 + 8] = cll[1];
    }
    __syncthreads();

#pragma unroll
    for (int tt = 0; tt < 4; ++tt) {
      Frag Af[2][2];
#pragma unroll
      for (int s = 0; s < 2; ++s)
#pragma unroll
        for (int p = 0; p < 2; ++p)
          Af[s][p].s8 = *(const short8*)&sP[p][(tt * 16 + c) * 80 + s * 32 + sq * 8];
      floatx4 x = (floatx4){0.f, 0.f, 0.f, 0.f};
#pragma unroll
      for (int s = 0; s < 2; ++s) {
        x = __builtin_amdgcn_mfma_f32_16x16x32_bf16(Af[s][0].s8, Bq[s][0].s8, x, 0, 0, 0);
        x = __builtin_amdgcn_mfma_f32_16x16x32_bf16(Af[s][0].s8, Bq[s][1].s8, x, 0, 0, 0);
        x = __builtin_amdgcn_mfma_f32_16x16x32_bf16(Af[s][1].s8, Bq[s][0].s8, x, 0, 0, 0);
      }
      float p4[4];
#pragma unroll
      for (int jj = 0; jj < 4; ++jj) {
        const float xp = x[jj];
        mxacc = fmaxf(mxacc, xp);
        p4[jj] = __expf(xp - diagc);
        dsacc = fmaf(p4[jj], sKs[mc * 64 + tt * 16 + sq * 4 + jj], dsacc);
      }
      const int kstep = tt >> 1;
      const int tl = ((tt & 1) * 2 + (sq >> 1)) * 16 + c;
      const int off = (sq & 1) * 4;
      float l0 = p4[0] - hif(p4[0]), l1 = p4[1] - hif(p4[1]);
      float l2 = p4[2] - hif(p4[2]), l3 = p4[3] - hif(p4[3]);
      *(uint2*)&sPhi[w][0][kstep][tl * 8 + off] = make_uint2(pk2(p4[0], p4[1]), pk2(p4[2], p4[3]));
      *(uint2*)&sPhi[w][1][kstep][tl * 8 + off] = make_uint2(pk2(l0, l1), pk2(l2, l3));
    }

#pragma unroll
    for (int ks = 0; ks < 2; ++ks) {
      Frag Aph[2];
      Aph[0].s8 = *(const short8*)&sPhi[w][0][ks][l * 8];
      Aph[1].s8 = *(const short8*)&sPhi[w][1][ks][l * 8];
#pragma unroll
      for (int E = 0; E < 4; ++E) {
        Frag Bc0, Bc1;
        Bc0.s8 = *(const short8*)&sC[0][(E * 16 + c) * 80 + ks * 32 + sq * 8];
        Bc1.s8 = *(const short8*)&sC[1][(E * 16 + c) * 80 + ks * 32 + sq * 8];
        oacc[E] = __builtin_amdgcn_mfma_f32_16x16x32_bf16(Aph[0].s8, Bc0.s8, oacc[E], 0, 0, 0);
        oacc[E] = __builtin_amdgcn_mfma_f32_16x16x32_bf16(Aph[0].s8, Bc1.s8, oacc[E], 0, 0, 0);
        oacc[E] = __builtin_amdgcn_mfma_f32_16x16x32_bf16(Aph[1].s8, Bc0.s8, oacc[E], 0, 0, 0);
      }
    }
  }

  mxacc = fmaxf(mxacc, __shfl_xor(mxacc, 16));
  mxacc = fmaxf(mxacc, __shfl_xor(mxacc, 32));
  dsacc += __shfl_xor(dsacc, 16);
  dsacc += __shfl_xor(dsacc, 32);

  const float kss = kssum[bh];
  float fac[4], oinv[4];
#pragma unroll
  for (int jj = 0; jj < 4; ++jj) {
    const int src = sq * 4 + jj;
    const float s_row = __shfl(mxacc, src);
    const float d_row = __shfl(dsacc, src);
    const float f = __expf(s_row) * EPSI;
    fac[jj] = f;
    oinv[jj] = 1.f / (d_row + f * kss);
  }

  const float* csb = ctxsum + bh * DD;
#pragma unroll
  for (int E = 0; E < 4; ++E) {
    const float cse = csb[E * 16 + c];
#pragma unroll
    for (int jj = 0; jj < 4; ++jj) {
      const int row = r0 + w * 16 + sq * 4 + jj;
      out[((size_t)bh * NN + row) * DD + E * 16 + c] =
          (oacc[E][jj] + fac[jj] * cse) * oinv[jj];
    }
  }
}

extern "C" void kernel_launch(void* const* d_in, const int* in_sizes, int n_in,
                              void* d_out, int out_size, void* d_ws, size_t ws_size,
                              hipStream_t stream) {
  const float* Q    = (const float*)d_in[0];
  const float* K    = (const float*)d_in[1];
  const float* V    = (const float*)d_in[2];
  const float* mask = (const float*)d_in[3];
  const float* proj = (const float*)d_in[4];
  float* out = (float*)d_out;

  float* wsf = (float*)d_ws;
  float* stabk  = wsf;                          // 32
  float* ksum   = wsf + 32;                     // 8192
  float* kssum  = wsf + 8224;                   // 32
  float* Vs     = wsf + 8256;                   // 2048
  float* ctxsum = wsf + 10304;                  // 2048
  float* ksE    = wsf + 12352;                  // 8192
  unsigned short* projH = (unsigned short*)(wsf + 20544);   // 16384 shorts
  unsigned short* projL = (unsigned short*)(wsf + 28736);   // 16384 shorts
  unsigned short* ctxTH = (unsigned short*)(wsf + 36928);   // 524288 shorts
  unsigned short* ctxTL = (unsigned short*)(wsf + 299072);  // 524288 shorts
  float* ctxBig = wsf + 561216;  // PARTIAL: NCH*32*16384 = 8388608 fl (33.5MB)
                                 // fallback: 524288 fl (ctxE)

  const size_t need_partial = (size_t)(561216 + NCH * BH * MM * DD) * 4;
  const bool partial = ws_size >= need_partial;

  prep_kernel<<<64, 256, 0, stream>>>(proj, projH, projL, stabk, Vs, ctxsum, ksE);

  if (partial) {
    kside_kernel<true><<<dim3(NCH, BH), 256, 0, stream>>>(
        K, V, mask, projH, projL, stabk, ksE, ctxBig, Vs);
    fixup_kernel<NCH><<<dim3(8, BH), 256, 0, stream>>>(
        stabk, Vs, ksE, ctxBig, ksum, kssum, ctxsum, ctxTH, ctxTL);
  } else {
    hipMemsetAsync(ctxBig, 0, (size_t)MM * DD * BH * 4, stream);
    kside_kernel<false><<<dim3(NCH, BH), 256, 0, stream>>>(
        K, V, mask, projH, projL, stabk, ksE, ctxBig, Vs);
    fixup_kernel<1><<<dim3(8, BH), 256, 0, stream>>>(
        stabk, Vs, ksE, ctxBig, ksum, kssum, ctxsum, ctxTH, ctxTL);
  }

  out_kernel<<<dim3(64, BH), 256, 0, stream>>>(
      Q, projH, projL, ksum, ctxTH, ctxTL, kssum, ctxsum, out);
}